// Round 6
// baseline (85.755 us; speedup 1.0000x reference)
//
#include <hip/hip_runtime.h>

#define STEPS 32
#define H 256
#define W 256
#define R 16               // rows per wave
#define WAVES 16           // 16 waves * 16 rows = 256 rows = whole image
#define NIMG 192

// bin(f) = ceil(f*31). Input uniform [0,1): k in [0,31], no clip needed
// (absmax exactly 0 in R1-R5). Monotone => bin(max(a,b)) = max(bin a, bin b).
__device__ __forceinline__ int binf(float f) {
    return (int)ceilf(f * 31.0f);
}

// Single-dispatch chain-form ECC. One 1024-thread block per (b,c) image:
// no cross-block merge -> plain stores, no memset dispatch, no global atomics.
// Chain algebra per column: sum(+v_i) - sum(max(v_i,v_{i+1})) telescopes to
// (+1@c, -1@n) per strictly-rising transition plus +1@v_255; h-edge/square
// chain is the same on he_i = max(v_i, v_i_right), negated.
// hist[k*64 + lane]: bank = lane%32 (2-way aliasing per wave64 = free);
// ds_add no-return atomics absorb cross-wave same-slot collisions.
__global__ __launch_bounds__(1024) void ecc_kernel(const float* __restrict__ x,
                                                   float* __restrict__ out) {
    __shared__ int hist[STEPS * 64];   // 8 KB
    const int tid  = threadIdx.x;
    const int lane = tid & 63;
    const int wave = tid >> 6;
    const int bc   = blockIdx.x;       // image*channel 0..191
    const int r0   = wave * R;
    // lane owns cols 4*lane..4*lane+3
    const float4* rowp = (const float4*)(x + (size_t)bc * (H * W)) + lane;

    hist[tid] = 0;
    hist[tid + 1024] = 0;
    __syncthreads();

    const bool has_right = (lane < 63);      // col 255 has no right edge
    const bool last_band = (wave == WAVES - 1);

#define ADD(k, v) atomicAdd(&hist[((k) << 6) + lane], (v))

    // 5-slot register queue, rows r0..r0+4 (r0+4 <= 244, always valid)
    float4 q[5];
#pragma unroll
    for (int t = 0; t < 5; ++t) q[t] = rowp[(size_t)(r0 + t) * (W / 4)];

    int c0 = binf(q[0].x), c1 = binf(q[0].y), c2 = binf(q[0].z), c3 = binf(q[0].w);
    int cR = __shfl_down(c0, 1);
    int h0 = max(c0, c1), h1 = max(c1, c2), h2 = max(c2, c3), h3 = max(c3, cR);

#pragma unroll
    for (int t = 0; t < R; ++t) {
        const bool down = (t < R - 1) || !last_band;   // wave-uniform
        if (down) {
            float4 nq = q[(t + 1) % 5];
            int n0 = binf(nq.x), n1 = binf(nq.y), n2 = binf(nq.z), n3 = binf(nq.w);
            int nR = __shfl_down(n0, 1);
            int g0 = max(n0, n1), g1 = max(n1, n2), g2 = max(n2, n3), g3 = max(n3, nR);
            // prefetch row r0+t+5 into the freed slot while still needed:
            // non-last waves consume rows up to r0+R, last wave up to r0+R-1
            if (t + 5 < R || (t + 5 == R && !last_band))
                q[t % 5] = rowp[(size_t)(r0 + t + 5) * (W / 4)];
            // vertex/v-edge chain: contribute only on strict rise
            if (n0 > c0) { ADD(c0, 1); ADD(n0, -1); }
            if (n1 > c1) { ADD(c1, 1); ADD(n1, -1); }
            if (n2 > c2) { ADD(c2, 1); ADD(n2, -1); }
            if (n3 > c3) { ADD(c3, 1); ADD(n3, -1); }
            // h-edge/square chain (negated): contribute only on strict rise
            if (g0 > h0) { ADD(h0, -1); ADD(g0, 1); }
            if (g1 > h1) { ADD(h1, -1); ADD(g1, 1); }
            if (g2 > h2) { ADD(h2, -1); ADD(g2, 1); }
            if (has_right && g3 > h3) { ADD(h3, -1); ADD(g3, 1); }
            c0 = n0; c1 = n1; c2 = n2; c3 = n3;
            h0 = g0; h1 = g1; h2 = g2; h3 = g3;
        } else {
            // i == 255 (last wave only): chain end terms = row-255 vertices (+)
            // and row-255 h-edges (-)
            ADD(c0, 1); ADD(c1, 1); ADD(c2, 1); ADD(c3, 1);
            ADD(h0, -1); ADD(h1, -1); ADD(h2, -1);
            if (has_right) ADD(h3, -1);
        }
    }
#undef ADD
    __syncthreads();

    // 32 threads: sum own bin over 64 columns (rotated => distinct banks),
    // 5-step shfl_up inclusive scan = cumsum, plain store (whole image owned
    // by this block -> no memset, no atomics).
    if (tid < STEPS) {
        int s = 0;
#pragma unroll 8
        for (int t = 0; t < 64; ++t)
            s += hist[(tid << 6) + ((t + tid) & 63)];
#pragma unroll
        for (int d = 1; d < STEPS; d <<= 1) {
            int u = __shfl_up(s, d);
            if (tid >= d) s += u;
        }
        out[bc * STEPS + tid] = (float)s;
    }
}

extern "C" void kernel_launch(void* const* d_in, const int* in_sizes, int n_in,
                              void* d_out, int out_size, void* d_ws, size_t ws_size,
                              hipStream_t stream) {
    const float* x = (const float*)d_in[0];
    float* out = (float*)d_out;
    // single dispatch: every out element is plain-stored by exactly one block
    ecc_kernel<<<NIMG, 1024, 0, stream>>>(x, out);
}

// Round 7
// 85.264 us; speedup vs baseline: 1.0058x; 1.0058x over previous
//
#include <hip/hip_runtime.h>

#define STEPS 32
#define H 256
#define W 256
#define R 8                // rows (positions) per wave band
#define NIMG 192
#define BLOCKS_PER_IMG 8   // 4 waves/block * 8 rows/wave = 32 rows/block

// bin(f) = ceil(f*31). Input uniform [0,1): k in [0,31], no clip needed
// (absmax exactly 0 in R1-R6). Monotone => bin(max(a,b)) = max(bin a, bin b).
__device__ __forceinline__ int binf(float f) {
    return (int)ceilf(f * 31.0f);
}

// Run-coalesced chain-form ECC. Per column, the vertex/v-edge telescoping
// extends across maximal rising runs: interior pair events cancel, leaving
// +1 at local minima (rise & !prev_rise) and -1 at local maxima
// (!rise & prev_rise) -- MUTUALLY EXCLUSIVE per position, and ds_add takes a
// per-lane VALUE as well as address, so ONE ds_add site per column per row
// covers both signs. H-edge/square chain: same on he = max(v, v_right),
// negated. End terms at row 255: +1@v iff !prev_rise, -1@he iff !prev_riseH.
// 8 ds_add sites/row-iter vs 16 in R4-R6 -- DS issue count (the kernel
// bottleneck) halves. Bands seed prev-flags by reading row r0-1 (LLC-warm).
// hist[k*64 + lane]: bank = lane%32, 2-way aliasing per wave64 = free.
__global__ __launch_bounds__(256) void ecc_kernel(const float* __restrict__ x,
                                                  float* __restrict__ out) {
    __shared__ int hist[STEPS * 64];   // 8 KB
    const int tid  = threadIdx.x;
    const int lane = tid & 63;
    const int wave = tid >> 6;
    const int bc   = blockIdx.x >> 3;  // image*channel 0..191
    const int bg   = blockIdx.x & 7;   // band group within image
    const int r0   = (bg * 4 + wave) * R;
    // lane owns cols 4*lane..4*lane+3
    const float4* rowp = (const float4*)(x + (size_t)bc * (H * W)) + lane;

#pragma unroll
    for (int w = 0; w < 8; ++w) hist[(w << 8) + tid] = 0;
    __syncthreads();

    const bool right = (lane < 63);    // col 255 has no h-edge chain
#define ADD(k, v) atomicAdd(&hist[((k) << 6) + lane], (v))

    // current row r0: vertex bins + h-edge bins
    float4 cq = rowp[(size_t)r0 * (W / 4)];
    int c0 = binf(cq.x), c1 = binf(cq.y), c2 = binf(cq.z), c3 = binf(cq.w);
    int cR = __shfl_down(c0, 1);
    int h0 = max(c0, c1), h1 = max(c1, c2), h2 = max(c2, c3), h3 = max(c3, cR);

    // seed prev-rise flags from row r0-1 (rise_{-1} = false for r0 == 0)
    bool pv0 = false, pv1 = false, pv2 = false, pv3 = false;
    bool ph0 = false, ph1 = false, ph2 = false, ph3 = false;
    if (r0 > 0) {                      // wave-uniform
        float4 mq = rowp[(size_t)(r0 - 1) * (W / 4)];
        int m0 = binf(mq.x), m1 = binf(mq.y), m2 = binf(mq.z), m3 = binf(mq.w);
        int mR = __shfl_down(m0, 1);
        int e0 = max(m0, m1), e1 = max(m1, m2), e2 = max(m2, m3), e3 = max(m3, mR);
        pv0 = c0 > m0; pv1 = c1 > m1; pv2 = c2 > m2; pv3 = c3 > m3;
        ph0 = h0 > e0; ph1 = h1 > e1; ph2 = h2 > e2; ph3 = h3 > e3;
    }

    const bool lastw = (r0 + R == H);  // this wave owns position 255
#pragma unroll
    for (int t = 0; t < R; ++t) {
        if (t < R - 1 || !lastw) {     // general position i = r0+t (uniform)
            float4 nq = rowp[(size_t)(r0 + t + 1) * (W / 4)];
            int n0 = binf(nq.x), n1 = binf(nq.y), n2 = binf(nq.z), n3 = binf(nq.w);
            int nR = __shfl_down(n0, 1);
            int g0 = max(n0, n1), g1 = max(n1, n2), g2 = max(n2, n3), g3 = max(n3, nR);
            // vertex chain: +1 at local min, -1 at local max (one site/col)
            bool rv0 = n0 > c0, rv1 = n1 > c1, rv2 = n2 > c2, rv3 = n3 > c3;
            if (rv0 != pv0) ADD(c0, rv0 ? 1 : -1);
            if (rv1 != pv1) ADD(c1, rv1 ? 1 : -1);
            if (rv2 != pv2) ADD(c2, rv2 ? 1 : -1);
            if (rv3 != pv3) ADD(c3, rv3 ? 1 : -1);
            // h-edge chain (negated): -1 at local min, +1 at local max
            bool rh0 = g0 > h0, rh1 = g1 > h1, rh2 = g2 > h2, rh3 = g3 > h3;
            if (rh0 != ph0) ADD(h0, rh0 ? -1 : 1);
            if (rh1 != ph1) ADD(h1, rh1 ? -1 : 1);
            if (rh2 != ph2) ADD(h2, rh2 ? -1 : 1);
            if (right && rh3 != ph3) ADD(h3, rh3 ? -1 : 1);
            pv0 = rv0; pv1 = rv1; pv2 = rv2; pv3 = rv3;
            ph0 = rh0; ph1 = rh1; ph2 = rh2; ph3 = rh3;
            c0 = n0; c1 = n1; c2 = n2; c3 = n3;
            h0 = g0; h1 = g1; h2 = g2; h3 = g3;
        } else {                       // global row 255: chain end terms
            if (!pv0) ADD(c0, 1);
            if (!pv1) ADD(c1, 1);
            if (!pv2) ADD(c2, 1);
            if (!pv3) ADD(c3, 1);
            if (!ph0) ADD(h0, -1);
            if (!ph1) ADD(h1, -1);
            if (!ph2) ADD(h2, -1);
            if (right && !ph3) ADD(h3, -1);
        }
    }
#undef ADD
    __syncthreads();

    // 32 threads: sum own bin over 64 columns (rotated => distinct banks),
    // 5-step shfl_up inclusive scan = cumsum, global atomic merges bands.
    if (tid < STEPS) {
        int s = 0;
#pragma unroll 8
        for (int t = 0; t < 64; ++t)
            s += hist[(tid << 6) + ((t + tid) & 63)];
#pragma unroll
        for (int d = 1; d < STEPS; d <<= 1) {
            int u = __shfl_up(s, d);
            if (tid >= d) s += u;
        }
        atomicAdd(&out[bc * STEPS + tid], (float)s);
    }
}

extern "C" void kernel_launch(void* const* d_in, const int* in_sizes, int n_in,
                              void* d_out, int out_size, void* d_ws, size_t ws_size,
                              hipStream_t stream) {
    const float* x = (const float*)d_in[0];
    float* out = (float*)d_out;
    // d_out is re-poisoned before every launch; we accumulate atomically into it.
    hipMemsetAsync(out, 0, (size_t)out_size * sizeof(float), stream);
    ecc_kernel<<<NIMG * BLOCKS_PER_IMG, 256, 0, stream>>>(x, out);
}